// Round 17
// baseline (603.338 us; speedup 1.0000x reference)
//
#include <hip/hip_runtime.h>
#include <hip/hip_bf16.h>
#include <cmath>

typedef __bf16 bf16;
typedef __attribute__((ext_vector_type(8))) __bf16 bf16x8;
typedef __attribute__((ext_vector_type(4))) __bf16 bf16x4;
typedef __attribute__((ext_vector_type(4))) float f32x4;
typedef unsigned long long ull;

#define TEMPC 65.0f
#define EPSC 1e-6f

#define GLD_LDS16(gptr, lptr)                                                             \
    __builtin_amdgcn_global_load_lds(                                                     \
        (const __attribute__((address_space(1))) unsigned int*)(gptr),                    \
        (__attribute__((address_space(3))) unsigned int*)(lptr), 16, 0, 0)

// ---------------- one-shot f32 -> bf16 convert: emb, Wih, Whh (R14-proven) ----------
__global__ void conv3_kernel(const float* __restrict__ e, bf16* __restrict__ eb,
                             const float* __restrict__ a, bf16* __restrict__ ab,
                             const float* __restrict__ b, bf16* __restrict__ bb)
{
    const int base   = (blockIdx.x * blockDim.x + threadIdx.x) * 4;
    const int stride = gridDim.x * blockDim.x * 4;
    for (int i = base; i < 32000 * 1024; i += stride) {
        const float4 v = *(const float4*)(e + i);
        bf16x4 o; o[0]=(bf16)v.x; o[1]=(bf16)v.y; o[2]=(bf16)v.z; o[3]=(bf16)v.w;
        *(bf16x4*)(eb + i) = o;
    }
    for (int i = base; i < 1024 * 1024; i += stride) {
        const float4 v = *(const float4*)(a + i);
        bf16x4 o; o[0]=(bf16)v.x; o[1]=(bf16)v.y; o[2]=(bf16)v.z; o[3]=(bf16)v.w;
        *(bf16x4*)(ab + i) = o;
    }
    for (int i = base; i < 1024 * 1024; i += stride) {
        const float4 v = *(const float4*)(b + i);
        bf16x4 o; o[0]=(bf16)v.x; o[1]=(bf16)v.y; o[2]=(bf16)v.z; o[3]=(bf16)v.w;
        *(bf16x4*)(bb + i) = o;
    }
}

// ---------------- FUSED (R14-proven): RNN (0-127) + XW-GEMM (128-639) + P-GEMM (640-2639)
// XWb is 0xFF-poisoned; XW tiles write it with packed 4B agent-atomic stores; RNN polls
// xw values for poison (retry deferred past the MFMA). pos term accumulated inline.
// P and Ust use plain stores (read only by the later neg kernel -> kernel-boundary
// coherence). No cross-role fences.
__global__ __launch_bounds__(256, 1)
void fused_kernel(const int* __restrict__ data, const bf16* __restrict__ emb,
                  const bf16* __restrict__ Wih, const float* __restrict__ bih,
                  bf16* __restrict__ P, bf16* __restrict__ raw,
                  const bf16* __restrict__ Whh, bf16* __restrict__ XWb,
                  const float* __restrict__ bhh, bf16* __restrict__ Ust,
                  int* __restrict__ cnt, float* __restrict__ lacc)
{
    __shared__ __align__(16) char pool[147584];   // rnn: 128K Wlds + 16.5K Hlds; gemm: 32K
    const int tid = threadIdx.x;
    const int l   = tid & 63;
    const int w   = tid >> 6;
    const int id  = blockIdx.x;

    if (id < 128) {
        // ================= RNN role (R9 sync structure, xw poison-poll, inline pos) ====
        bf16* Wlds = (bf16*)pool;                    // 128KB
        char* Hlds = pool + 131072;                  // 8 rows x 2064B
        const int group  = id & 7;
        const int slot   = id >> 3;                  // 0..15: j-slice
        const int jbase  = slot * 64;
        const int frow   = l & 15;
        const int kchunk = l >> 4;
        const int jglob  = jbase + w * 16 + frow;
        const int rr     = frow & 7;

        {   // stage Whh j-slice (128KB), source pre-swizzled (kc ^= (j>>1)&3)
            const int jloc = l >> 2;
            const int csw  = ((l & 3) ^ ((l >> 3) & 3)) * 16;
            const char* gsrc = (const char*)Whh + (size_t)(jbase + w * 16 + jloc) * 2048 + csw;
            for (int kk = 0; kk < 32; ++kk)
                GLD_LDS16(gsrc + kk * 64, Wlds + (kk * 4 + w) * 512);
            asm volatile("s_waitcnt vmcnt(0)" ::: "memory");
            __syncthreads();
        }
        const float bh = bhh[jglob];

        const int ksw   = kchunk ^ ((frow >> 1) & 3);
        const bf16* wrd = Wlds + w * 512 + frow * 32 + ksw * 8;   // +kk*2048 per k-block
        const char* hrd = Hlds + rr * 2064 + kchunk * 16;         // +kk*64 per k-block
        const int jpair = jglob & ~1;
        float posacc = 0.f;

        for (int t = 0; t < 128; ++t) {
            if (t > 0) {
                if (tid < 4)                 // parallel poll: 4 sub-counters x 4 adds
                    while (__hip_atomic_load(&cnt[((t * 8 + group) * 4 + tid) * 32],
                                             __ATOMIC_RELAXED, __HIP_MEMORY_SCOPE_AGENT) < 4)
                        __builtin_amdgcn_s_sleep(1);
                __syncthreads();
            }
            // cooperative coherent fetch of group h_t (16KB): 256 thr x 8 x 8B
            const ull* hsrc8 = (const ull*)(raw + (size_t)t * 65536 + group * 8192);
            ull hv[8];
            #pragma unroll
            for (int i = 0; i < 8; ++i)
                hv[i] = __hip_atomic_load(hsrc8 + tid + i * 256,
                                          __ATOMIC_RELAXED, __HIP_MEMORY_SCOPE_AGENT);
            // xw: coherent 4B loads (pair of bf16 cols); poison-retry deferred past MFMA
            unsigned int xww[4];
            #pragma unroll
            for (int r = 0; r < 4; ++r) {
                const int bc = (kchunk * 4 + r) & 7;
                const size_t row = (size_t)(t * 64 + group * 8 + bc);
                xww[r] = __hip_atomic_load((const unsigned int*)(XWb + row * 1024 + jpair),
                                           __ATOMIC_RELAXED, __HIP_MEMORY_SCOPE_AGENT);
            }
            #pragma unroll
            for (int i = 0; i < 8; ++i)
                *(ull*)(Hlds + i * 2064 + tid * 8) = hv[i];
            __syncthreads();

            f32x4 acc0 = {0.f,0.f,0.f,0.f}, acc1 = {0.f,0.f,0.f,0.f};
            #pragma unroll
            for (int kk = 0; kk < 32; kk += 2) {
                bf16x8 a0 = *(const bf16x8*)(hrd + kk * 64);
                bf16x8 a1 = *(const bf16x8*)(hrd + kk * 64 + 64);
                acc0 = __builtin_amdgcn_mfma_f32_16x16x32_bf16(a0, *(const bf16x8*)(wrd + kk * 2048),       acc0, 0, 0, 0);
                acc1 = __builtin_amdgcn_mfma_f32_16x16x32_bf16(a1, *(const bf16x8*)(wrd + (kk + 1) * 2048), acc1, 0, 0, 0);
            }

            // resolve xw (values are never bf16 0xFFFF; whole word 0xFFFFFFFF = poison)
            for (;;) {
                bool bad = false;
                #pragma unroll
                for (int r = 0; r < 4; ++r) bad |= (xww[r] == 0xFFFFFFFFu);
                if (!bad) break;
                #pragma unroll
                for (int r = 0; r < 4; ++r)
                    if (xww[r] == 0xFFFFFFFFu) {
                        const int bc = (kchunk * 4 + r) & 7;
                        const size_t row = (size_t)(t * 64 + group * 8 + bc);
                        xww[r] = __hip_atomic_load((const unsigned int*)(XWb + row * 1024 + jpair),
                                                   __ATOMIC_RELAXED, __HIP_MEMORY_SCOPE_AGENT);
                    }
            }

            bf16* rawN = raw + (size_t)(t + 1) * 65536;
            if (l < 32) {                            // rows 0-7 real
                #pragma unroll
                for (int r = 0; r < 4; ++r) {
                    const int b = (l >> 4) * 4 + r;
                    const unsigned short x16 = (jglob & 1) ? (unsigned short)(xww[r] >> 16)
                                                           : (unsigned short)(xww[r] & 0xFFFF);
                    const float xwv = __builtin_bit_cast(float, (unsigned int)x16 << 16);
                    const float V = acc0[r] + acc1[r] + bh;          // h @ Whh^T + b_hh
                    const float h = tanhf(xwv + V);                  // xw holds + b_ih
                    const size_t row = (size_t)(t * 64 + group * 8 + b);
                    Ust[row * 1024 + jglob] = (bf16)V;               // hiddens_U (no b_ih)
                    const bf16 hb = (bf16)h;
                    // inline pos: (h_t - h_{t+1} + eps)^2 at (b, jglob)
                    const float ht = (float)*(const bf16*)(Hlds + b * 2064 + jglob * 2);
                    const float pd = ht - (float)hb + EPSC;
                    posacc += pd * pd;
                    unsigned short hs = __builtin_bit_cast(unsigned short, hb);
                    unsigned short hn = (unsigned short)__shfl_down((int)hs, 1, 64);
                    if ((frow & 1) == 0) {                           // pack 2 cols -> 4B
                        unsigned int pack = (unsigned int)hs | ((unsigned int)hn << 16);
                        unsigned int* dst = (unsigned int*)(rawN + (size_t)(group * 8 + b) * 1024 + jglob);
                        __hip_atomic_store(dst, pack, __ATOMIC_RELAXED, __HIP_MEMORY_SCOPE_AGENT);
                    }
                }
            }
            if (t < 127) {
                __syncthreads();                     // store acks drained
                if (tid == 0)
                    __hip_atomic_fetch_add(&cnt[(((t + 1) * 8 + group) * 4 + (slot & 3)) * 32], 1,
                                           __ATOMIC_RELAXED, __HIP_MEMORY_SCOPE_AGENT);
            }
        }
        // pos partial: wave-reduce + one atomicAdd
        #pragma unroll
        for (int off2 = 32; off2 > 0; off2 >>= 1) posacc += __shfl_down(posacc, off2, 64);
        if (l == 0) atomicAdd(lacc, posacc * (TEMPC / 128.f));
    } else {
        // ================= GEMM roles: 128x128 tile, BK=32, dbuf, counted vmcnt ========
        bf16* As = (bf16*)pool;                      // 16KB (2 bufs)
        bf16* Bs = (bf16*)(pool + 16384);            // 16KB
        const int wr = w >> 1, wc = w & 1;
        const bool isXW = (id < 640);

        int mbase, nbase;
        const char *Asrc0, *Asrc1;
        const int r0 = w * 32 + (l >> 2);
        const int csw = ((l & 3) ^ ((l >> 3) & 3)) * 16;
        if (isXW) {
            const int q = id - 128;                  // mi-ascending: earliest rows first
            mbase = (q >> 3) * 128;
            nbase = (q & 7) * 128;
            Asrc0 = (const char*)emb + (size_t)data[mbase + r0] * 2048 + csw;
            Asrc1 = (const char*)emb + (size_t)data[mbase + r0 + 16] * 2048 + csw;
        } else {
            const int q  = id - 640;                 // 0..1999
            const int wg = (q & 7) * 250 + (q >> 3); // XCD swizzle
            mbase = (wg >> 3) * 128;
            nbase = (wg & 7) * 128;
            Asrc0 = (const char*)emb + (size_t)(mbase + r0) * 2048 + csw;
            Asrc1 = (const char*)emb + (size_t)(mbase + r0 + 16) * 2048 + csw;
        }
        const char* Bsrc0 = (const char*)Wih + (size_t)(nbase + r0) * 2048 + csw;
        const char* Bsrc1 = (const char*)Wih + (size_t)(nbase + r0 + 16) * 2048 + csw;

        const int frow  = l & 15;
        const int koffE = (((l >> 4) ^ ((frow >> 1) & 3)) * 8);
        const bf16* Ard = As + (wr * 64 + frow) * 32 + koffE;
        const bf16* Brd = Bs + (wc * 64 + frow) * 32 + koffE;

        auto stage = [&](int buf, int kb) {
            bf16* As_ = As + buf * 4096 + w * 1024;
            bf16* Bs_ = Bs + buf * 4096 + w * 1024;
            GLD_LDS16(Asrc0 + kb, As_);
            GLD_LDS16(Asrc1 + kb, As_ + 512);
            GLD_LDS16(Bsrc0 + kb, Bs_);
            GLD_LDS16(Bsrc1 + kb, Bs_ + 512);
        };

        stage(0, 0);
        stage(1, 64);

        f32x4 acc[4][4] = {};
        for (int k = 0; k < 32; ++k) {
            if (k == 31) asm volatile("s_waitcnt vmcnt(0)" ::: "memory");
            else         asm volatile("s_waitcnt vmcnt(4)" ::: "memory");
            __builtin_amdgcn_s_barrier();
            const bf16* Ab = Ard + (k & 1) * 4096;
            const bf16* Bb = Brd + (k & 1) * 4096;
            bf16x8 af[4], bfr[4];
            #pragma unroll
            for (int mt = 0; mt < 4; ++mt) af[mt]  = *(const bf16x8*)(Ab + mt * 16 * 32);
            #pragma unroll
            for (int nt = 0; nt < 4; ++nt) bfr[nt] = *(const bf16x8*)(Bb + nt * 16 * 32);
            #pragma unroll
            for (int mt = 0; mt < 4; ++mt)
                #pragma unroll
                for (int nt = 0; nt < 4; ++nt)
                    acc[mt][nt] = __builtin_amdgcn_mfma_f32_16x16x32_bf16(af[mt], bfr[nt], acc[mt][nt], 0, 0, 0);
            asm volatile("s_waitcnt lgkmcnt(0)" ::: "memory");
            __builtin_amdgcn_s_barrier();
            if (k + 2 < 32) stage(k & 1, (k + 2) * 64);
        }

        if (isXW) {
            // packed 4B agent-atomic stores (write-through -> RNN sees them; un-poisons)
            #pragma unroll
            for (int mt = 0; mt < 4; ++mt)
                #pragma unroll
                for (int nt = 0; nt < 4; ++nt) {
                    const int colg = nbase + wc * 64 + nt * 16 + frow;
                    const float bi = bih[colg];
                    #pragma unroll
                    for (int r = 0; r < 4; ++r) {
                        const int rowg = mbase + wr * 64 + mt * 16 + (l >> 4) * 4 + r;
                        const bf16 vb = (bf16)(acc[mt][nt][r] + bi);
                        unsigned short vs = __builtin_bit_cast(unsigned short, vb);
                        unsigned short vn = (unsigned short)__shfl_down((int)vs, 1, 64);
                        if ((frow & 1) == 0) {
                            unsigned int pack = (unsigned int)vs | ((unsigned int)vn << 16);
                            __hip_atomic_store((unsigned int*)(XWb + (size_t)rowg * 1024 + colg),
                                               pack, __ATOMIC_RELAXED, __HIP_MEMORY_SCOPE_AGENT);
                        }
                    }
                }
        } else {
            // plain stores: P is consumed only by the next kernel (boundary coherence)
            #pragma unroll
            for (int mt = 0; mt < 4; ++mt)
                #pragma unroll
                for (int nt = 0; nt < 4; ++nt) {
                    const int colg = nbase + wc * 64 + nt * 16 + frow;
                    const float bi = bih[colg];
                    #pragma unroll
                    for (int r = 0; r < 4; ++r) {
                        const int rowg = mbase + wr * 64 + mt * 16 + (l >> 4) * 4 + r;
                        P[(size_t)rowg * 1024 + colg] = (bf16)(acc[mt][nt][r] + bi);
                    }
                }
        }
    }
}

// ---------------- neg term + finalize: per row r, log-mean-exp of clipped dist --------
// Separate kernel (R14-proven): plain loads, coherence via kernel boundary. Last block
// to finish (negdone counter) writes the final loss to out.
__global__ __launch_bounds__(256)
void neg_kernel(const int* __restrict__ samples, const bf16* __restrict__ P,
                const bf16* __restrict__ Ust, const bf16* __restrict__ raw,
                float* __restrict__ lacc, int* __restrict__ negdone,
                float* __restrict__ out)
{
    const int l = threadIdx.x & 63;
    const int r = blockIdx.x * 4 + (threadIdx.x >> 6);   // row 0..8191
    const bf16* u  = Ust + (size_t)r * 1024;
    const bf16* pv = raw + (size_t)r * 1024;

    float uf[16], vf[16];
    {
        bf16x8 u0 = *(const bf16x8*)(u + l * 8);
        bf16x8 u1 = *(const bf16x8*)(u + 512 + l * 8);
        bf16x8 v0 = *(const bf16x8*)(pv + l * 8);
        bf16x8 v1 = *(const bf16x8*)(pv + 512 + l * 8);
        #pragma unroll
        for (int i = 0; i < 8; ++i) {
            uf[i] = (float)u0[i]; uf[8 + i] = (float)u1[i];
            vf[i] = (float)v0[i]; vf[8 + i] = (float)v1[i];
        }
    }

    float se = 0.f;
    #pragma unroll
    for (int s = 0; s < 10; ++s) {
        const int tok = samples[s * 8192 + r];
        const bf16* pr = P + (size_t)tok * 1024;
        bf16x8 p0 = *(const bf16x8*)(pr + l * 8);
        bf16x8 p1 = *(const bf16x8*)(pr + 512 + l * 8);
        float d2 = 0.f;
        #pragma unroll
        for (int i = 0; i < 8; ++i) {
            const float o0 = tanhf((float)p0[i] + uf[i]);
            const float d0 = vf[i] - o0 + EPSC;
            d2 += d0 * d0;
            const float o1 = tanhf((float)p1[i] + uf[8 + i]);
            const float d1 = vf[8 + i] - o1 + EPSC;
            d2 += d1 * d1;
        }
        #pragma unroll
        for (int off = 1; off < 64; off <<= 1)
            d2 += __shfl_xor(d2, off, 64);
        se += expf(-fminf(d2, 0.01f));               // d2 >= 0 already
    }
    if (l == 0) atomicAdd(lacc, logf(se * (1.f / 8192.f) + EPSC));

    __syncthreads();                                 // all 4 waves' adds drained
    if (threadIdx.x == 0) {
        const int old = __hip_atomic_fetch_add(negdone, 1, __ATOMIC_ACQ_REL,
                                               __HIP_MEMORY_SCOPE_AGENT);
        if (old == 2047)                             // last block: finalize
            out[0] = __hip_atomic_load(lacc, __ATOMIC_RELAXED, __HIP_MEMORY_SCOPE_AGENT);
    }
}

extern "C" void kernel_launch(void* const* d_in, const int* in_sizes, int n_in,
                              void* d_out, int out_size, void* d_ws, size_t ws_size,
                              hipStream_t stream)
{
    const int*   data    = (const int*)d_in[0];   // [128*64]
    const int*   samples = (const int*)d_in[1];   // [10*8192]
    const float* emb     = (const float*)d_in[2]; // [32000*1024]
    const float* Wih     = (const float*)d_in[3]; // [1024*1024]
    const float* bih     = (const float*)d_in[4]; // [1024]
    const float* Whh     = (const float*)d_in[5]; // [1024*1024]
    const float* bhh     = (const float*)d_in[6]; // [1024]

    char* ws = (char*)d_ws;
    size_t off = 0;
    auto alloc = [&](size_t bytes) { void* p = ws + off; off += (bytes + 255) & ~(size_t)255; return p; };
    bf16*  emb_b = (bf16*)alloc((size_t)32000 * 1024 * 2);
    bf16*  Wih_b = (bf16*)alloc((size_t)1024 * 1024 * 2);
    bf16*  Whh_b = (bf16*)alloc((size_t)1024 * 1024 * 2);
    bf16*  P     = (bf16*)alloc((size_t)32000 * 1024 * 2);
    bf16*  XWb   = (bf16*)alloc((size_t)8192 * 1024 * 2);
    bf16*  Ust   = (bf16*)alloc((size_t)8192 * 1024 * 2);
    bf16*  raw   = (bf16*)alloc((size_t)129 * 64 * 1024 * 2);
    int*   cnt   = (int*)alloc(524288);           // step counters
    float* lacc  = (float*)alloc(256);            // adjacent to cnt: single memset
    int*   negdone = (int*)(lacc + 16);

    hipMemsetAsync(raw, 0, 64 * 1024 * 2, stream);                    // h0 = 0
    hipMemsetAsync(XWb, 0xFF, (size_t)8192 * 1024 * 2, stream);       // poison XWb
    hipMemsetAsync(cnt, 0, 524288 + 256, stream);                     // cnt + lacc + negdone

    // all three f32->bf16 conversions in one launch
    conv3_kernel<<<2048, 256, 0, stream>>>(emb, emb_b, Wih, Wih_b, Whh, Whh_b);

    // FUSED: 128 RNN blocks + 512 XWb tiles (priority) + 2000 P tiles
    fused_kernel<<<2640, 256, 0, stream>>>(data, emb_b, Wih_b, bih, P,
                                           raw, Whh_b, XWb, bhh, Ust, cnt, lacc);

    // neg term + finalize (last block writes out)
    neg_kernel<<<2048, 256, 0, stream>>>(samples, P, Ust, raw, lacc, negdone,
                                         (float*)d_out);
}

// Round 18
// 585.631 us; speedup vs baseline: 1.0302x; 1.0302x over previous
//
#include <hip/hip_runtime.h>
#include <hip/hip_bf16.h>
#include <cmath>

typedef __bf16 bf16;
typedef __attribute__((ext_vector_type(8))) __bf16 bf16x8;
typedef __attribute__((ext_vector_type(4))) __bf16 bf16x4;
typedef __attribute__((ext_vector_type(4))) float f32x4;
typedef unsigned long long ull;

#define TEMPC 65.0f
#define EPSC 1e-6f

#define GLD_LDS16(gptr, lptr)                                                             \
    __builtin_amdgcn_global_load_lds(                                                     \
        (const __attribute__((address_space(1))) unsigned int*)(gptr),                    \
        (__attribute__((address_space(3))) unsigned int*)(lptr), 16, 0, 0)

// ---------------- one-shot f32 -> bf16 convert: emb, Wih, Whh ----------------
__global__ void conv3_kernel(const float* __restrict__ e, bf16* __restrict__ eb,
                             const float* __restrict__ a, bf16* __restrict__ ab,
                             const float* __restrict__ b, bf16* __restrict__ bb)
{
    const int base   = (blockIdx.x * blockDim.x + threadIdx.x) * 4;
    const int stride = gridDim.x * blockDim.x * 4;
    for (int i = base; i < 32000 * 1024; i += stride) {
        const float4 v = *(const float4*)(e + i);
        bf16x4 o; o[0]=(bf16)v.x; o[1]=(bf16)v.y; o[2]=(bf16)v.z; o[3]=(bf16)v.w;
        *(bf16x4*)(eb + i) = o;
    }
    for (int i = base; i < 1024 * 1024; i += stride) {
        const float4 v = *(const float4*)(a + i);
        bf16x4 o; o[0]=(bf16)v.x; o[1]=(bf16)v.y; o[2]=(bf16)v.z; o[3]=(bf16)v.w;
        *(bf16x4*)(ab + i) = o;
    }
    for (int i = base; i < 1024 * 1024; i += stride) {
        const float4 v = *(const float4*)(b + i);
        bf16x4 o; o[0]=(bf16)v.x; o[1]=(bf16)v.y; o[2]=(bf16)v.z; o[3]=(bf16)v.w;
        *(bf16x4*)(bb + i) = o;
    }
}

// ---------------- FUSED: RNN (0-127) + XW-GEMM (128-639) + P-GEMM (640-2639) ----------
// XWb is 0xFF-poisoned; XW tiles write packed 4B agent-atomic stores; RNN polls xw
// values for poison (retry deferred past MFMA). pos accumulated inline. P/Ust plain
// stores (consumed next kernel -> boundary coherence). No cross-role fences.
__global__ __launch_bounds__(256, 1)
void fused_kernel(const int* __restrict__ data, const bf16* __restrict__ emb,
                  const bf16* __restrict__ Wih, const float* __restrict__ bih,
                  bf16* __restrict__ P, bf16* __restrict__ raw,
                  const bf16* __restrict__ Whh, bf16* __restrict__ XWb,
                  const float* __restrict__ bhh, bf16* __restrict__ Ust,
                  int* __restrict__ cnt, float* __restrict__ lacc)
{
    __shared__ __align__(16) char pool[147584];   // rnn: 128K Wlds + 16.5K Hlds; gemm: 32K
    const int tid = threadIdx.x;
    const int l   = tid & 63;
    const int w   = tid >> 6;
    const int id  = blockIdx.x;

    if (id < 128) {
        // ================= RNN role =================
        bf16* Wlds = (bf16*)pool;                    // 128KB
        char* Hlds = pool + 131072;                  // 8 rows x 2064B
        const int group  = id & 7;
        const int slot   = id >> 3;                  // 0..15: j-slice
        const int jbase  = slot * 64;
        const int frow   = l & 15;
        const int kchunk = l >> 4;
        const int jglob  = jbase + w * 16 + frow;
        const int rr     = frow & 7;

        {   // stage Whh j-slice (128KB), source pre-swizzled (kc ^= (j>>1)&3)
            const int jloc = l >> 2;
            const int csw  = ((l & 3) ^ ((l >> 3) & 3)) * 16;
            const char* gsrc = (const char*)Whh + (size_t)(jbase + w * 16 + jloc) * 2048 + csw;
            for (int kk = 0; kk < 32; ++kk)
                GLD_LDS16(gsrc + kk * 64, Wlds + (kk * 4 + w) * 512);
            asm volatile("s_waitcnt vmcnt(0)" ::: "memory");
            __syncthreads();
        }
        const float bh = bhh[jglob];

        const int ksw   = kchunk ^ ((frow >> 1) & 3);
        const bf16* wrd = Wlds + w * 512 + frow * 32 + ksw * 8;   // +kk*2048 per k-block
        const char* hrd = Hlds + rr * 2064 + kchunk * 16;         // +kk*64 per k-block
        const int jpair = jglob & ~1;
        float posacc = 0.f;

        for (int t = 0; t < 128; ++t) {
            if (t > 0) {
                if (tid < 4)                 // parallel poll: 4 sub-counters x 4 adds
                    while (__hip_atomic_load(&cnt[((t * 8 + group) * 4 + tid) * 32],
                                             __ATOMIC_RELAXED, __HIP_MEMORY_SCOPE_AGENT) < 4)
                        __builtin_amdgcn_s_sleep(1);
                __syncthreads();
            }
            // cooperative coherent fetch of group h_t (16KB): 256 thr x 8 x 8B
            const ull* hsrc8 = (const ull*)(raw + (size_t)t * 65536 + group * 8192);
            ull hv[8];
            #pragma unroll
            for (int i = 0; i < 8; ++i)
                hv[i] = __hip_atomic_load(hsrc8 + tid + i * 256,
                                          __ATOMIC_RELAXED, __HIP_MEMORY_SCOPE_AGENT);
            // xw: coherent 4B loads; poison-retry deferred past MFMA
            unsigned int xww[4];
            #pragma unroll
            for (int r = 0; r < 4; ++r) {
                const int bc = (kchunk * 4 + r) & 7;
                const size_t row = (size_t)(t * 64 + group * 8 + bc);
                xww[r] = __hip_atomic_load((const unsigned int*)(XWb + row * 1024 + jpair),
                                           __ATOMIC_RELAXED, __HIP_MEMORY_SCOPE_AGENT);
            }
            #pragma unroll
            for (int i = 0; i < 8; ++i)
                *(ull*)(Hlds + i * 2064 + tid * 8) = hv[i];
            __syncthreads();

            f32x4 acc0 = {0.f,0.f,0.f,0.f}, acc1 = {0.f,0.f,0.f,0.f};
            #pragma unroll
            for (int kk = 0; kk < 32; kk += 2) {
                bf16x8 a0 = *(const bf16x8*)(hrd + kk * 64);
                bf16x8 a1 = *(const bf16x8*)(hrd + kk * 64 + 64);
                acc0 = __builtin_amdgcn_mfma_f32_16x16x32_bf16(a0, *(const bf16x8*)(wrd + kk * 2048),       acc0, 0, 0, 0);
                acc1 = __builtin_amdgcn_mfma_f32_16x16x32_bf16(a1, *(const bf16x8*)(wrd + (kk + 1) * 2048), acc1, 0, 0, 0);
            }

            for (;;) {      // resolve xw poison (values never 0xFFFFFFFF)
                bool bad = false;
                #pragma unroll
                for (int r = 0; r < 4; ++r) bad |= (xww[r] == 0xFFFFFFFFu);
                if (!bad) break;
                #pragma unroll
                for (int r = 0; r < 4; ++r)
                    if (xww[r] == 0xFFFFFFFFu) {
                        const int bc = (kchunk * 4 + r) & 7;
                        const size_t row = (size_t)(t * 64 + group * 8 + bc);
                        xww[r] = __hip_atomic_load((const unsigned int*)(XWb + row * 1024 + jpair),
                                                   __ATOMIC_RELAXED, __HIP_MEMORY_SCOPE_AGENT);
                    }
            }

            bf16* rawN = raw + (size_t)(t + 1) * 65536;
            if (l < 32) {                            // rows 0-7 real
                #pragma unroll
                for (int r = 0; r < 4; ++r) {
                    const int b = (l >> 4) * 4 + r;
                    const unsigned short x16 = (jglob & 1) ? (unsigned short)(xww[r] >> 16)
                                                           : (unsigned short)(xww[r] & 0xFFFF);
                    const float xwv = __builtin_bit_cast(float, (unsigned int)x16 << 16);
                    const float V = acc0[r] + acc1[r] + bh;          // h @ Whh^T + b_hh
                    const float h = tanhf(xwv + V);                  // xw holds + b_ih
                    const size_t row = (size_t)(t * 64 + group * 8 + b);
                    Ust[row * 1024 + jglob] = (bf16)V;               // hiddens_U (no b_ih)
                    const bf16 hb = (bf16)h;
                    const float ht = (float)*(const bf16*)(Hlds + b * 2064 + jglob * 2);
                    const float pd = ht - (float)hb + EPSC;          // inline pos term
                    posacc += pd * pd;
                    unsigned short hs = __builtin_bit_cast(unsigned short, hb);
                    unsigned short hn = (unsigned short)__shfl_down((int)hs, 1, 64);
                    if ((frow & 1) == 0) {                           // pack 2 cols -> 4B
                        unsigned int pack = (unsigned int)hs | ((unsigned int)hn << 16);
                        unsigned int* dst = (unsigned int*)(rawN + (size_t)(group * 8 + b) * 1024 + jglob);
                        __hip_atomic_store(dst, pack, __ATOMIC_RELAXED, __HIP_MEMORY_SCOPE_AGENT);
                    }
                }
            }
            if (t < 127) {
                __syncthreads();                     // store acks drained
                if (tid == 0)
                    __hip_atomic_fetch_add(&cnt[(((t + 1) * 8 + group) * 4 + (slot & 3)) * 32], 1,
                                           __ATOMIC_RELAXED, __HIP_MEMORY_SCOPE_AGENT);
            }
        }
        #pragma unroll
        for (int off2 = 32; off2 > 0; off2 >>= 1) posacc += __shfl_down(posacc, off2, 64);
        if (l == 0) atomicAdd(lacc, posacc * (TEMPC / 128.f));
    } else {
        // ================= GEMM roles: 128x128 tile, BK=32, dbuf, counted vmcnt ========
        bf16* As = (bf16*)pool;                      // 16KB (2 bufs)
        bf16* Bs = (bf16*)(pool + 16384);            // 16KB
        const int wr = w >> 1, wc = w & 1;
        const bool isXW = (id < 640);

        int mbase, nbase;
        const char *Asrc0, *Asrc1;
        const int r0 = w * 32 + (l >> 2);
        const int csw = ((l & 3) ^ ((l >> 3) & 3)) * 16;
        if (isXW) {
            const int q = id - 128;                  // mi-ascending: earliest rows first
            mbase = (q >> 3) * 128;
            nbase = (q & 7) * 128;
            Asrc0 = (const char*)emb + (size_t)data[mbase + r0] * 2048 + csw;
            Asrc1 = (const char*)emb + (size_t)data[mbase + r0 + 16] * 2048 + csw;
        } else {
            const int q  = id - 640;                 // 0..1999
            const int wg = (q & 7) * 250 + (q >> 3); // XCD swizzle
            mbase = (wg >> 3) * 128;
            nbase = (wg & 7) * 128;
            Asrc0 = (const char*)emb + (size_t)(mbase + r0) * 2048 + csw;
            Asrc1 = (const char*)emb + (size_t)(mbase + r0 + 16) * 2048 + csw;
        }
        const char* Bsrc0 = (const char*)Wih + (size_t)(nbase + r0) * 2048 + csw;
        const char* Bsrc1 = (const char*)Wih + (size_t)(nbase + r0 + 16) * 2048 + csw;

        const int frow  = l & 15;
        const int koffE = (((l >> 4) ^ ((frow >> 1) & 3)) * 8);
        const bf16* Ard = As + (wr * 64 + frow) * 32 + koffE;
        const bf16* Brd = Bs + (wc * 64 + frow) * 32 + koffE;

        auto stage = [&](int buf, int kb) {
            bf16* As_ = As + buf * 4096 + w * 1024;
            bf16* Bs_ = Bs + buf * 4096 + w * 1024;
            GLD_LDS16(Asrc0 + kb, As_);
            GLD_LDS16(Asrc1 + kb, As_ + 512);
            GLD_LDS16(Bsrc0 + kb, Bs_);
            GLD_LDS16(Bsrc1 + kb, Bs_ + 512);
        };

        stage(0, 0);
        stage(1, 64);

        f32x4 acc[4][4] = {};
        for (int k = 0; k < 32; ++k) {
            if (k == 31) asm volatile("s_waitcnt vmcnt(0)" ::: "memory");
            else         asm volatile("s_waitcnt vmcnt(4)" ::: "memory");
            __builtin_amdgcn_s_barrier();
            const bf16* Ab = Ard + (k & 1) * 4096;
            const bf16* Bb = Brd + (k & 1) * 4096;
            bf16x8 af[4], bfr[4];
            #pragma unroll
            for (int mt = 0; mt < 4; ++mt) af[mt]  = *(const bf16x8*)(Ab + mt * 16 * 32);
            #pragma unroll
            for (int nt = 0; nt < 4; ++nt) bfr[nt] = *(const bf16x8*)(Bb + nt * 16 * 32);
            #pragma unroll
            for (int mt = 0; mt < 4; ++mt)
                #pragma unroll
                for (int nt = 0; nt < 4; ++nt)
                    acc[mt][nt] = __builtin_amdgcn_mfma_f32_16x16x32_bf16(af[mt], bfr[nt], acc[mt][nt], 0, 0, 0);
            asm volatile("s_waitcnt lgkmcnt(0)" ::: "memory");
            __builtin_amdgcn_s_barrier();
            if (k + 2 < 32) stage(k & 1, (k + 2) * 64);
        }

        if (isXW) {
            #pragma unroll
            for (int mt = 0; mt < 4; ++mt)
                #pragma unroll
                for (int nt = 0; nt < 4; ++nt) {
                    const int colg = nbase + wc * 64 + nt * 16 + frow;
                    const float bi = bih[colg];
                    #pragma unroll
                    for (int r = 0; r < 4; ++r) {
                        const int rowg = mbase + wr * 64 + mt * 16 + (l >> 4) * 4 + r;
                        const bf16 vb = (bf16)(acc[mt][nt][r] + bi);
                        unsigned short vs = __builtin_bit_cast(unsigned short, vb);
                        unsigned short vn = (unsigned short)__shfl_down((int)vs, 1, 64);
                        if ((frow & 1) == 0) {
                            unsigned int pack = (unsigned int)vs | ((unsigned int)vn << 16);
                            __hip_atomic_store((unsigned int*)(XWb + (size_t)rowg * 1024 + colg),
                                               pack, __ATOMIC_RELAXED, __HIP_MEMORY_SCOPE_AGENT);
                        }
                    }
                }
        } else {
            #pragma unroll
            for (int mt = 0; mt < 4; ++mt)
                #pragma unroll
                for (int nt = 0; nt < 4; ++nt) {
                    const int colg = nbase + wc * 64 + nt * 16 + frow;
                    const float bi = bih[colg];
                    #pragma unroll
                    for (int r = 0; r < 4; ++r) {
                        const int rowg = mbase + wr * 64 + mt * 16 + (l >> 4) * 4 + r;
                        P[(size_t)rowg * 1024 + colg] = (bf16)(acc[mt][nt][r] + bi);
                    }
                }
        }
    }
}

// ---------------- neg term + finalize (software-pipelined sample loop) ----------------
__global__ __launch_bounds__(256)
void neg_kernel(const int* __restrict__ samples, const bf16* __restrict__ P,
                const bf16* __restrict__ Ust, const bf16* __restrict__ raw,
                float* __restrict__ lacc, int* __restrict__ negdone,
                float* __restrict__ out)
{
    const int l = threadIdx.x & 63;
    const int r = blockIdx.x * 4 + (threadIdx.x >> 6);   // row 0..8191
    const bf16* u  = Ust + (size_t)r * 1024;
    const bf16* pv = raw + (size_t)r * 1024;

    float uf[16], vf[16];
    {
        bf16x8 u0 = *(const bf16x8*)(u + l * 8);
        bf16x8 u1 = *(const bf16x8*)(u + 512 + l * 8);
        bf16x8 v0 = *(const bf16x8*)(pv + l * 8);
        bf16x8 v1 = *(const bf16x8*)(pv + 512 + l * 8);
        #pragma unroll
        for (int i = 0; i < 8; ++i) {
            uf[i] = (float)u0[i]; uf[8 + i] = (float)u1[i];
            vf[i] = (float)v0[i]; vf[8 + i] = (float)v1[i];
        }
    }

    // software pipeline: gather loads of sample s+1 issue before compute of sample s
    int tok = samples[r];
    const bf16* pr = P + (size_t)tok * 1024;
    bf16x8 p0 = *(const bf16x8*)(pr + l * 8);
    bf16x8 p1 = *(const bf16x8*)(pr + 512 + l * 8);

    float se = 0.f;
    #pragma unroll
    for (int s = 0; s < 10; ++s) {
        const bf16x8 c0 = p0, c1 = p1;
        if (s + 1 < 10) {                            // issue next gather NOW
            tok = samples[(s + 1) * 8192 + r];
            const bf16* prn = P + (size_t)tok * 1024;
            p0 = *(const bf16x8*)(prn + l * 8);
            p1 = *(const bf16x8*)(prn + 512 + l * 8);
        }
        float d2 = 0.f;
        #pragma unroll
        for (int i = 0; i < 8; ++i) {
            const float o0 = tanhf((float)c0[i] + uf[i]);
            const float d0 = vf[i] - o0 + EPSC;
            d2 += d0 * d0;
            const float o1 = tanhf((float)c1[i] + uf[8 + i]);
            const float d1 = vf[8 + i] - o1 + EPSC;
            d2 += d1 * d1;
        }
        #pragma unroll
        for (int off = 1; off < 64; off <<= 1)
            d2 += __shfl_xor(d2, off, 64);
        se += expf(-fminf(d2, 0.01f));
    }
    if (l == 0) atomicAdd(lacc, logf(se * (1.f / 8192.f) + EPSC));

    __syncthreads();                                 // all 4 waves' adds drained
    if (threadIdx.x == 0) {
        const int old = __hip_atomic_fetch_add(negdone, 1, __ATOMIC_ACQ_REL,
                                               __HIP_MEMORY_SCOPE_AGENT);
        if (old == 2047)                             // last block: finalize
            out[0] = __hip_atomic_load(lacc, __ATOMIC_RELAXED, __HIP_MEMORY_SCOPE_AGENT);
    }
}

extern "C" void kernel_launch(void* const* d_in, const int* in_sizes, int n_in,
                              void* d_out, int out_size, void* d_ws, size_t ws_size,
                              hipStream_t stream)
{
    const int*   data    = (const int*)d_in[0];   // [128*64]
    const int*   samples = (const int*)d_in[1];   // [10*8192]
    const float* emb     = (const float*)d_in[2]; // [32000*1024]
    const float* Wih     = (const float*)d_in[3]; // [1024*1024]
    const float* bih     = (const float*)d_in[4]; // [1024]
    const float* Whh     = (const float*)d_in[5]; // [1024*1024]
    const float* bhh     = (const float*)d_in[6]; // [1024]

    char* ws = (char*)d_ws;
    size_t off = 0;
    auto alloc = [&](size_t bytes) { void* p = ws + off; off += (bytes + 255) & ~(size_t)255; return p; };
    bf16*  emb_b = (bf16*)alloc((size_t)32000 * 1024 * 2);
    bf16*  Wih_b = (bf16*)alloc((size_t)1024 * 1024 * 2);
    bf16*  Whh_b = (bf16*)alloc((size_t)1024 * 1024 * 2);
    bf16*  P     = (bf16*)alloc((size_t)32000 * 1024 * 2);
    bf16*  XWb   = (bf16*)alloc((size_t)8192 * 1024 * 2);
    bf16*  Ust   = (bf16*)alloc((size_t)8192 * 1024 * 2);
    bf16*  raw   = (bf16*)alloc((size_t)129 * 64 * 1024 * 2);
    int*   cnt   = (int*)alloc(524288);           // step counters
    float* lacc  = (float*)alloc(256);            // adjacent to cnt: single memset
    int*   negdone = (int*)(lacc + 16);

    hipMemsetAsync(raw, 0, 64 * 1024 * 2, stream);                    // h0 = 0
    hipMemsetAsync(XWb, 0xFF, (size_t)8192 * 1024 * 2, stream);       // poison XWb
    hipMemsetAsync(cnt, 0, 524288 + 256, stream);                     // cnt + lacc + negdone

    conv3_kernel<<<2048, 256, 0, stream>>>(emb, emb_b, Wih, Wih_b, Whh, Whh_b);

    // FUSED: 128 RNN blocks + 512 XWb tiles (priority) + 2000 P tiles
    fused_kernel<<<2640, 256, 0, stream>>>(data, emb_b, Wih_b, bih, P,
                                           raw, Whh_b, XWb, bhh, Ust, cnt, lacc);

    // neg term + finalize (last block writes out)
    neg_kernel<<<2048, 256, 0, stream>>>(samples, P, Ust, raw, lacc, negdone,
                                         (float*)d_out);
}